// Round 3
// baseline (14413.683 us; speedup 1.0000x reference)
//
#include <hip/hip_runtime.h>
#include <hip/hip_bf16.h>

#define SEQ 118
#define NBLK 8192

typedef __attribute__((ext_vector_type(8))) short short8;
typedef __attribute__((ext_vector_type(4))) float f32x4;

__device__ __forceinline__ f32x4 mfma16(short8 a, short8 b, f32x4 c){
  return __builtin_amdgcn_mfma_f32_16x16x32_bf16(a, b, c, 0, 0, 0);
}
__device__ __forceinline__ float bfr(float x){            // bf16 RNE round-trip
  return __bfloat162float(__float2bfloat16(x));
}
__device__ __forceinline__ float rsum16(float v){
  v += __shfl_xor(v,1); v += __shfl_xor(v,2); v += __shfl_xor(v,4); v += __shfl_xor(v,8);
  return v;
}
__device__ __forceinline__ float rmax16(float v){
  v = fmaxf(v, __shfl_xor(v,1)); v = fmaxf(v, __shfl_xor(v,2));
  v = fmaxf(v, __shfl_xor(v,4)); v = fmaxf(v, __shfl_xor(v,8));
  return v;
}

__global__ void prep_kernel(const float* __restrict__ qkv_w,
                            const float* __restrict__ fc2_w,
                            __hip_bfloat16* __restrict__ wbf){
  int i = blockIdx.x * 256 + threadIdx.x;   // 65536 total
  if (i < 384*128) wbf[i] = __float2bfloat16(qkv_w[i]);
  else             wbf[i] = __float2bfloat16(fc2_w[i - 384*128]);
}

// LDS = 132 KB -> exactly 1 block/CU -> exactly 2 waves/EU resident.
// Rounds 1-2: compiler capped VGPRs at 128 (4-waves/EU budget) -> massive
// scratch spill (17.5 GB HBM writes/dispatch). __launch_bounds__(512,2) did
// NOT lift the cap. Talk to the backend directly: min 1 wave/EU -> VGPR cap
// 512; max 2 matches the real LDS-bound occupancy.
__global__ __attribute__((amdgpu_flat_work_group_size(512, 512),
                          amdgpu_waves_per_eu(1, 2)))
void fused_kernel(const float* __restrict__ x,
                             const float* __restrict__ fc1_w, const float* __restrict__ fc1_b,
                             const float* __restrict__ qkv_b,
                             const float* __restrict__ fc2_b, const float* __restrict__ fc3_w,
                             const float* __restrict__ fc3_b,
                             const float* __restrict__ ln_g,  const float* __restrict__ ln_b,
                             const __hip_bfloat16* __restrict__ wqkv,   // [384][128] bf16
                             const __hip_bfloat16* __restrict__ wfc2,   // [128][128] bf16
                             float* __restrict__ out)
{
  // 32 KB activations / P-scratch; 32 KB each Q (also Y), K, V^T (head-major)
  __shared__ __hip_bfloat16 sA [128*128];
  __shared__ __hip_bfloat16 sQ [4*128*32];
  __shared__ __hip_bfloat16 sK [4*128*32];
  __shared__ __hip_bfloat16 sVt[4*32*128];
  __shared__ float sO1[128];
  __shared__ float sCb[896];   // qkv_b(384) fc2_b(128) fc3_w(128) ln_g(128) ln_b(128)

  const int b    = blockIdx.x;
  const int tid  = threadIdx.x;
  const int wv   = tid >> 6;        // wave 0..7 -> 16-row strip
  const int lane = tid & 63;
  const int c    = lane & 15;
  const int quad = lane >> 4;

  for (int i = tid; i < 896; i += 512){
    float v;
    if      (i < 384) v = qkv_b[i];
    else if (i < 512) v = fc2_b[i-384];
    else if (i < 640) v = fc3_w[i-512];
    else if (i < 768) v = ln_g [i-640];
    else              v = ln_b [i-768];
    sCb[i] = v;
  }
  { // h = silu(x*fc1_w + fc1_b); padded rows (s>=118) zeroed
    int s  = tid >> 2;
    int d0 = (tid & 3) * 32;
    float xs = (s < SEQ) ? x[b*SEQ + s] : 0.f;
    #pragma unroll 8
    for (int i = 0; i < 32; i++){
      int d = d0 + i;
      float v = 0.f;
      if (s < SEQ){
        float z = xs * fc1_w[d] + fc1_b[d];
        v = z / (1.f + __expf(-z));
      }
      sA[s*128 + d] = __float2bfloat16(v);
    }
  }
  __syncthreads();

  const float* sQB = sCb;
  const float* sFB = sCb + 384;
  const float* sW3 = sCb + 512;
  const float* sLG = sCb + 640;
  const float* sLB = sCb + 768;

  for (int p = 0; p < 2; ++p){
    // ================= QKV GEMM (M-strip per wave) =================
    short8 afr[4];
    #pragma unroll
    for (int k4 = 0; k4 < 4; k4++)
      afr[k4] = *(const short8*)(sA + (wv*16 + c)*128 + k4*32 + quad*8);

    // q & k tile-pairs (d, d+64) with RoPE epilogue
    for (int t = 0; t < 4; ++t){
      const int d0 = t*16 + c;                      // 0..63
      f32x4 aq0={0,0,0,0}, aq1={0,0,0,0}, ak0={0,0,0,0}, ak1={0,0,0,0};
      #pragma unroll
      for (int k4 = 0; k4 < 4; k4++){
        const __hip_bfloat16* wp = wqkv + k4*32 + quad*8;
        short8 b0 = *(const short8*)(wp + (d0      )*128);
        short8 b1 = *(const short8*)(wp + (d0 +  64)*128);
        short8 b2 = *(const short8*)(wp + (d0 + 128)*128);
        short8 b3 = *(const short8*)(wp + (d0 + 192)*128);
        aq0 = mfma16(afr[k4], b0, aq0);
        aq1 = mfma16(afr[k4], b1, aq1);
        ak0 = mfma16(afr[k4], b2, ak0);
        ak1 = mfma16(afr[k4], b3, ak1);
      }
      float bq0 = sQB[d0], bq1 = sQB[d0+64], bk0 = sQB[128+d0], bk1 = sQB[192+d0];
      float invf = exp2f((float)d0 * (-13.287712379549449f/64.f)); // 10000^(-d0/64)
      int hh = d0 & 3, dh = d0 >> 2;
      __hip_bfloat16* q_p = sQ + hh*4096;
      __hip_bfloat16* k_p = sK + hh*4096;
      #pragma unroll
      for (int j = 0; j < 4; j++){
        int s = wv*16 + quad*4 + j;
        float ang = (float)s * invf;
        float cv = bfr(__cosf(ang));
        float sv = bfr(__sinf(ang));
        float q1 = aq0[j] + bq0, q2 = aq1[j] + bq1;
        float k1 = ak0[j] + bk0, k2 = ak1[j] + bk1;
        q_p[s*32 + dh     ] = __float2bfloat16( q1*cv + q2*sv);
        q_p[s*32 + dh + 16] = __float2bfloat16(-q1*sv + q2*cv);
        k_p[s*32 + dh     ] = __float2bfloat16( k1*cv + k2*sv);
        k_p[s*32 + dh + 16] = __float2bfloat16(-k1*sv + k2*cv);
      }
    }
    // v tiles -> transposed store sVt[h][dh][s]
    for (int t = 0; t < 8; ++t){
      const int d0 = t*16 + c;                      // 0..127
      f32x4 av = {0,0,0,0};
      #pragma unroll
      for (int k4 = 0; k4 < 4; k4++){
        short8 bv = *(const short8*)(wqkv + (256 + d0)*128 + k4*32 + quad*8);
        av = mfma16(afr[k4], bv, av);
      }
      float bias = sQB[256 + d0];
      int hh = d0 & 3, dh = d0 >> 2;
      __hip_bfloat16* vp = sVt + hh*4096 + dh*128 + wv*16 + quad*4;
      #pragma unroll
      for (int j = 0; j < 4; j++) vp[j] = __float2bfloat16(av[j] + bias);
    }
    __syncthreads();   // Q/K/Vt visible to all waves

    // ================= attention (no barriers inside) =================
    for (int h = 0; h < 4; ++h){
      const int st = (h & 1) ? (7 - wv) : wv;       // balanced causal strips
      short8 aq = *(const short8*)(sQ + h*4096 + (st*16 + c)*32 + quad*8);
      f32x4 sc[8];
      #pragma unroll
      for (int t = 0; t < 8; ++t){
        if (t <= st){
          short8 bk = *(const short8*)(sK + h*4096 + (t*16 + c)*32 + quad*8);
          f32x4 z = {0,0,0,0};
          sc[t] = mfma16(aq, bk, z);
        }
      }
      const int ntp = (st + 2) & ~1;                // P tiles padded to even
      const float scale = 0.17677669529663687f;     // 1/sqrt(32)
      #pragma unroll
      for (int j = 0; j < 4; j++){
        const int s = st*16 + quad*4 + j;
        float mx = -3.0e38f;
        #pragma unroll
        for (int t = 0; t < 8; t++){
          if (t <= st){
            float v = ((t*16 + c) <= s) ? sc[t][j]*scale : -1.0e9f;
            sc[t][j] = v;
            mx = fmaxf(mx, v);
          }
        }
        mx = rmax16(mx);
        float sum = 0.f;
        #pragma unroll
        for (int t = 0; t < 8; t++){
          if (t <= st){
            float e = __expf(sc[t][j] - mx);
            sc[t][j] = e;
            sum += e;
          }
        }
        sum = rsum16(sum);
        float r = 1.f / sum;
        #pragma unroll
        for (int t = 0; t < 8; t++){
          if (t < ntp){
            float pv = (t <= st) ? sc[t][j]*r : 0.f; // zero-pad odd tile
            sA[(wv*16 + quad*4 + j)*128 + t*16 + c] = __float2bfloat16(pv);
          }
        }
      }
      // P @ V  (P rows indexed by WAVE -> race-free across heads)
      f32x4 y0 = {0,0,0,0}, y1 = {0,0,0,0};
      const int K4 = ntp >> 1;
      #pragma unroll
      for (int kk = 0; kk < 4; kk++){
        if (kk < K4){
          short8 ap  = *(const short8*)(sA  + (wv*16 + c)*128 + kk*32 + quad*8);
          short8 bv0 = *(const short8*)(sVt + h*4096 + (c     )*128 + kk*32 + quad*8);
          short8 bv1 = *(const short8*)(sVt + h*4096 + (16 + c)*128 + kk*32 + quad*8);
          y0 = mfma16(ap, bv0, y0);
          y1 = mfma16(ap, bv1, y1);
        }
      }
      #pragma unroll
      for (int j = 0; j < 4; j++){
        int s = st*16 + quad*4 + j;
        sQ[h*4096 + s*32 + c     ] = __float2bfloat16(y0[j]);   // Y overwrites Q
        sQ[h*4096 + s*32 + 16 + c] = __float2bfloat16(y1[j]);
      }
    }
    __syncthreads();   // Y strips written by two waves each -> fc2 needs all

    // ================= FC2 + fused epilogue =================
    short8 ay[4];
    #pragma unroll
    for (int k4 = 0; k4 < 4; k4++)
      ay[k4] = *(const short8*)(sQ + k4*4096 + (wv*16 + c)*32 + quad*8);
    f32x4 xx[8];
    #pragma unroll
    for (int t = 0; t < 8; t++){
      f32x4 acc = {0,0,0,0};
      #pragma unroll
      for (int k4 = 0; k4 < 4; k4++){
        short8 bw = *(const short8*)(wfc2 + (t*16 + c)*128 + k4*32 + quad*8);
        acc = mfma16(ay[k4], bw, acc);
      }
      float bias = sFB[t*16 + c];
      #pragma unroll
      for (int j = 0; j < 4; j++){
        float z = acc[j] + bias;
        xx[t][j] = z / (1.f + __expf(-z));          // silu
      }
    }
    #pragma unroll
    for (int j = 0; j < 4; j++){
      float s1 = 0.f, s2 = 0.f, s3 = 0.f;
      #pragma unroll
      for (int t = 0; t < 8; t++){
        float v = xx[t][j];
        s1 += v; s2 += v*v; s3 += v * sW3[t*16 + c];
      }
      s1 = rsum16(s1); s2 = rsum16(s2); s3 = rsum16(s3);
      const int s = wv*16 + quad*4 + j;
      if (p == 0){
        float mu  = s1 * (1.f/128.f);
        float var = fmaxf(s2 * (1.f/128.f) - mu*mu, 0.f);  // clamp: NaN guard
        float rs  = rsqrtf(var + 1e-5f);
        #pragma unroll
        for (int t = 0; t < 8; t++){
          int d = t*16 + c;
          sA[s*128 + d] = __float2bfloat16((xx[t][j] - mu)*rs*sLG[d] + sLB[d]);
        }
        if (c == 0) sO1[s] = s3;                    // x1 . fc3_w  (residual readout)
      } else {
        if (c == 0 && s < SEQ) out[b*SEQ + s] = sO1[s] + s3 + fc3_b[0];
      }
    }
    // no barrier needed: all cross-pass LDS hand-offs are wave-private strips
  }
}

extern "C" void kernel_launch(void* const* d_in, const int* in_sizes, int n_in,
                              void* d_out, int out_size, void* d_ws, size_t ws_size,
                              hipStream_t stream){
  const float* x     = (const float*)d_in[0];
  const float* fc1_w = (const float*)d_in[1];
  const float* fc1_b = (const float*)d_in[2];
  const float* qkv_w = (const float*)d_in[3];
  const float* qkv_b = (const float*)d_in[4];
  const float* fc2_w = (const float*)d_in[5];
  const float* fc2_b = (const float*)d_in[6];
  const float* fc3_w = (const float*)d_in[7];
  const float* fc3_b = (const float*)d_in[8];
  const float* ln_g  = (const float*)d_in[9];
  const float* ln_b  = (const float*)d_in[10];

  __hip_bfloat16* wbf = (__hip_bfloat16*)d_ws;        // 384*128 + 128*128 bf16
  prep_kernel<<<256, 256, 0, stream>>>(qkv_w, fc2_w, wbf);

  const int B = in_sizes[0] / SEQ;                    // 8192
  fused_kernel<<<B, 512, 0, stream>>>(x, fc1_w, fc1_b, qkv_b, fc2_b, fc3_w, fc3_b,
                                      ln_g, ln_b, wbf, wbf + 384*128, (float*)d_out);
}

// Round 4
// 6974.751 us; speedup vs baseline: 2.0666x; 2.0666x over previous
//
#include <hip/hip_runtime.h>
#include <hip/hip_bf16.h>

#define SEQ 118
#define NBLK 8192

typedef __attribute__((ext_vector_type(8))) short short8;
typedef __attribute__((ext_vector_type(4))) float f32x4;

__device__ __forceinline__ f32x4 mfma16(short8 a, short8 b, f32x4 c){
  return __builtin_amdgcn_mfma_f32_16x16x32_bf16(a, b, c, 0, 0, 0);
}
__device__ __forceinline__ float bfr(float x){            // bf16 RNE round-trip
  return __bfloat162float(__float2bfloat16(x));
}
__device__ __forceinline__ float rsum16(float v){
  v += __shfl_xor(v,1); v += __shfl_xor(v,2); v += __shfl_xor(v,4); v += __shfl_xor(v,8);
  return v;
}
__device__ __forceinline__ float rmax16(float v){
  v = fmaxf(v, __shfl_xor(v,1)); v = fmaxf(v, __shfl_xor(v,2));
  v = fmaxf(v, __shfl_xor(v,4)); v = fmaxf(v, __shfl_xor(v,8));
  return v;
}

__global__ void prep_kernel(const float* __restrict__ qkv_w,
                            const float* __restrict__ fc2_w,
                            __hip_bfloat16* __restrict__ wbf){
  int i = blockIdx.x * 256 + threadIdx.x;   // 65536 total
  if (i < 384*128) wbf[i] = __float2bfloat16(qkv_w[i]);
  else             wbf[i] = __float2bfloat16(fc2_w[i - 384*128]);
}

// Rounds 1-3: full unroll of the phase loops ballooned the live set past the
// 128-VGPR budget -> scratch spill -> 30 GB HBM traffic/dispatch (the entire
// 14 ms). Occupancy attributes were ineffective (bit-identical binaries), so
// instead we keep each phase-loop body small with #pragma unroll 1; every
// register array is indexed only from still-unrolled inner loops.
__global__ __attribute__((amdgpu_flat_work_group_size(512, 512),
                          amdgpu_waves_per_eu(1, 2)))
void fused_kernel(const float* __restrict__ x,
                             const float* __restrict__ fc1_w, const float* __restrict__ fc1_b,
                             const float* __restrict__ qkv_b,
                             const float* __restrict__ fc2_b, const float* __restrict__ fc3_w,
                             const float* __restrict__ fc3_b,
                             const float* __restrict__ ln_g,  const float* __restrict__ ln_b,
                             const __hip_bfloat16* __restrict__ wqkv,   // [384][128] bf16
                             const __hip_bfloat16* __restrict__ wfc2,   // [128][128] bf16
                             float* __restrict__ out)
{
  // 32 KB activations / P-scratch; 32 KB each Q (also Y), K, V^T (head-major)
  __shared__ __hip_bfloat16 sA [128*128];
  __shared__ __hip_bfloat16 sQ [4*128*32];
  __shared__ __hip_bfloat16 sK [4*128*32];
  __shared__ __hip_bfloat16 sVt[4*32*128];
  __shared__ float sO1[128];
  __shared__ float sCb[896];   // qkv_b(384) fc2_b(128) fc3_w(128) ln_g(128) ln_b(128)

  const int b    = blockIdx.x;
  const int tid  = threadIdx.x;
  const int wv   = tid >> 6;        // wave 0..7 -> 16-row strip
  const int lane = tid & 63;
  const int c    = lane & 15;
  const int quad = lane >> 4;

  for (int i = tid; i < 896; i += 512){
    float v;
    if      (i < 384) v = qkv_b[i];
    else if (i < 512) v = fc2_b[i-384];
    else if (i < 640) v = fc3_w[i-512];
    else if (i < 768) v = ln_g [i-640];
    else              v = ln_b [i-768];
    sCb[i] = v;
  }
  { // h = silu(x*fc1_w + fc1_b); padded rows (s>=118) zeroed
    int s  = tid >> 2;
    int d0 = (tid & 3) * 32;
    float xs = (s < SEQ) ? x[b*SEQ + s] : 0.f;
    #pragma unroll 8
    for (int i = 0; i < 32; i++){
      int d = d0 + i;
      float v = 0.f;
      if (s < SEQ){
        float z = xs * fc1_w[d] + fc1_b[d];
        v = z / (1.f + __expf(-z));
      }
      sA[s*128 + d] = __float2bfloat16(v);
    }
  }
  __syncthreads();

  const float* sQB = sCb;
  const float* sFB = sCb + 384;
  const float* sW3 = sCb + 512;
  const float* sLG = sCb + 640;
  const float* sLB = sCb + 768;

  #pragma unroll 1
  for (int p = 0; p < 2; ++p){
    // ================= QKV GEMM (M-strip per wave) =================
    short8 afr[4];
    #pragma unroll
    for (int k4 = 0; k4 < 4; k4++)
      afr[k4] = *(const short8*)(sA + (wv*16 + c)*128 + k4*32 + quad*8);

    // q & k tile-pairs (d, d+64) with RoPE epilogue
    #pragma unroll 1
    for (int t = 0; t < 4; ++t){
      const int d0 = t*16 + c;                      // 0..63
      f32x4 aq0={0,0,0,0}, aq1={0,0,0,0}, ak0={0,0,0,0}, ak1={0,0,0,0};
      #pragma unroll
      for (int k4 = 0; k4 < 4; k4++){
        const __hip_bfloat16* wp = wqkv + k4*32 + quad*8;
        short8 b0 = *(const short8*)(wp + (d0      )*128);
        short8 b1 = *(const short8*)(wp + (d0 +  64)*128);
        short8 b2 = *(const short8*)(wp + (d0 + 128)*128);
        short8 b3 = *(const short8*)(wp + (d0 + 192)*128);
        aq0 = mfma16(afr[k4], b0, aq0);
        aq1 = mfma16(afr[k4], b1, aq1);
        ak0 = mfma16(afr[k4], b2, ak0);
        ak1 = mfma16(afr[k4], b3, ak1);
      }
      float bq0 = sQB[d0], bq1 = sQB[d0+64], bk0 = sQB[128+d0], bk1 = sQB[192+d0];
      float invf = exp2f((float)d0 * (-13.287712379549449f/64.f)); // 10000^(-d0/64)
      int hh = d0 & 3, dh = d0 >> 2;
      __hip_bfloat16* q_p = sQ + hh*4096;
      __hip_bfloat16* k_p = sK + hh*4096;
      #pragma unroll
      for (int j = 0; j < 4; j++){
        int s = wv*16 + quad*4 + j;
        float ang = (float)s * invf;
        float cv = bfr(__cosf(ang));
        float sv = bfr(__sinf(ang));
        float q1 = aq0[j] + bq0, q2 = aq1[j] + bq1;
        float k1 = ak0[j] + bk0, k2 = ak1[j] + bk1;
        q_p[s*32 + dh     ] = __float2bfloat16( q1*cv + q2*sv);
        q_p[s*32 + dh + 16] = __float2bfloat16(-q1*sv + q2*cv);
        k_p[s*32 + dh     ] = __float2bfloat16( k1*cv + k2*sv);
        k_p[s*32 + dh + 16] = __float2bfloat16(-k1*sv + k2*cv);
      }
    }
    // v tiles -> transposed store sVt[h][dh][s]
    #pragma unroll 1
    for (int t = 0; t < 8; ++t){
      const int d0 = t*16 + c;                      // 0..127
      f32x4 av = {0,0,0,0};
      #pragma unroll
      for (int k4 = 0; k4 < 4; k4++){
        short8 bv = *(const short8*)(wqkv + (256 + d0)*128 + k4*32 + quad*8);
        av = mfma16(afr[k4], bv, av);
      }
      float bias = sQB[256 + d0];
      int hh = d0 & 3, dh = d0 >> 2;
      __hip_bfloat16* vp = sVt + hh*4096 + dh*128 + wv*16 + quad*4;
      #pragma unroll
      for (int j = 0; j < 4; j++) vp[j] = __float2bfloat16(av[j] + bias);
    }
    __syncthreads();   // Q/K/Vt visible to all waves

    // ================= attention (no barriers inside) =================
    #pragma unroll 1
    for (int h = 0; h < 4; ++h){
      const int st = (h & 1) ? (7 - wv) : wv;       // balanced causal strips
      short8 aq = *(const short8*)(sQ + h*4096 + (st*16 + c)*32 + quad*8);
      f32x4 sc[8];
      #pragma unroll
      for (int t = 0; t < 8; ++t){
        if (t <= st){
          short8 bk = *(const short8*)(sK + h*4096 + (t*16 + c)*32 + quad*8);
          f32x4 z = {0,0,0,0};
          sc[t] = mfma16(aq, bk, z);
        }
      }
      const int ntp = (st + 2) & ~1;                // P tiles padded to even
      const float scale = 0.17677669529663687f;     // 1/sqrt(32)
      #pragma unroll
      for (int j = 0; j < 4; j++){
        const int s = st*16 + quad*4 + j;
        float mx = -3.0e38f;
        #pragma unroll
        for (int t = 0; t < 8; t++){
          if (t <= st){
            float v = ((t*16 + c) <= s) ? sc[t][j]*scale : -1.0e9f;
            sc[t][j] = v;
            mx = fmaxf(mx, v);
          }
        }
        mx = rmax16(mx);
        float sum = 0.f;
        #pragma unroll
        for (int t = 0; t < 8; t++){
          if (t <= st){
            float e = __expf(sc[t][j] - mx);
            sc[t][j] = e;
            sum += e;
          }
        }
        sum = rsum16(sum);
        float r = 1.f / sum;
        #pragma unroll
        for (int t = 0; t < 8; t++){
          if (t < ntp){
            float pv = (t <= st) ? sc[t][j]*r : 0.f; // zero-pad odd tile
            sA[(wv*16 + quad*4 + j)*128 + t*16 + c] = __float2bfloat16(pv);
          }
        }
      }
      // P @ V  (P rows indexed by WAVE -> race-free across heads)
      f32x4 y0 = {0,0,0,0}, y1 = {0,0,0,0};
      const int K4 = ntp >> 1;
      #pragma unroll
      for (int kk = 0; kk < 4; kk++){
        if (kk < K4){
          short8 ap  = *(const short8*)(sA  + (wv*16 + c)*128 + kk*32 + quad*8);
          short8 bv0 = *(const short8*)(sVt + h*4096 + (c     )*128 + kk*32 + quad*8);
          short8 bv1 = *(const short8*)(sVt + h*4096 + (16 + c)*128 + kk*32 + quad*8);
          y0 = mfma16(ap, bv0, y0);
          y1 = mfma16(ap, bv1, y1);
        }
      }
      #pragma unroll
      for (int j = 0; j < 4; j++){
        int s = st*16 + quad*4 + j;
        sQ[h*4096 + s*32 + c     ] = __float2bfloat16(y0[j]);   // Y overwrites Q
        sQ[h*4096 + s*32 + 16 + c] = __float2bfloat16(y1[j]);
      }
    }
    __syncthreads();   // Y strips written by two waves each -> fc2 needs all

    // ================= FC2 + fused epilogue =================
    short8 ay[4];
    #pragma unroll
    for (int k4 = 0; k4 < 4; k4++)
      ay[k4] = *(const short8*)(sQ + k4*4096 + (wv*16 + c)*32 + quad*8);
    f32x4 xx[8];
    #pragma unroll 1
    for (int t = 0; t < 8; t++){
      f32x4 acc = {0,0,0,0};
      #pragma unroll
      for (int k4 = 0; k4 < 4; k4++){
        short8 bw = *(const short8*)(wfc2 + (t*16 + c)*128 + k4*32 + quad*8);
        acc = mfma16(ay[k4], bw, acc);
      }
      float bias = sFB[t*16 + c];
      #pragma unroll
      for (int j = 0; j < 4; j++){
        float z = acc[j] + bias;
        xx[t][j] = z / (1.f + __expf(-z));          // silu
      }
    }
    #pragma unroll
    for (int j = 0; j < 4; j++){
      float s1 = 0.f, s2 = 0.f, s3 = 0.f;
      #pragma unroll
      for (int t = 0; t < 8; t++){
        float v = xx[t][j];
        s1 += v; s2 += v*v; s3 += v * sW3[t*16 + c];
      }
      s1 = rsum16(s1); s2 = rsum16(s2); s3 = rsum16(s3);
      const int s = wv*16 + quad*4 + j;
      if (p == 0){
        float mu  = s1 * (1.f/128.f);
        float var = fmaxf(s2 * (1.f/128.f) - mu*mu, 0.f);  // clamp: NaN guard
        float rs  = rsqrtf(var + 1e-5f);
        #pragma unroll
        for (int t = 0; t < 8; t++){
          int d = t*16 + c;
          sA[s*128 + d] = __float2bfloat16((xx[t][j] - mu)*rs*sLG[d] + sLB[d]);
        }
        if (c == 0) sO1[s] = s3;                    // x1 . fc3_w  (residual readout)
      } else {
        if (c == 0 && s < SEQ) out[b*SEQ + s] = sO1[s] + s3 + fc3_b[0];
      }
    }
    // no barrier needed: all cross-pass LDS hand-offs are wave-private strips
  }
}

extern "C" void kernel_launch(void* const* d_in, const int* in_sizes, int n_in,
                              void* d_out, int out_size, void* d_ws, size_t ws_size,
                              hipStream_t stream){
  const float* x     = (const float*)d_in[0];
  const float* fc1_w = (const float*)d_in[1];
  const float* fc1_b = (const float*)d_in[2];
  const float* qkv_w = (const float*)d_in[3];
  const float* qkv_b = (const float*)d_in[4];
  const float* fc2_w = (const float*)d_in[5];
  const float* fc2_b = (const float*)d_in[6];
  const float* fc3_w = (const float*)d_in[7];
  const float* fc3_b = (const float*)d_in[8];
  const float* ln_g  = (const float*)d_in[9];
  const float* ln_b  = (const float*)d_in[10];

  __hip_bfloat16* wbf = (__hip_bfloat16*)d_ws;        // 384*128 + 128*128 bf16
  prep_kernel<<<256, 256, 0, stream>>>(qkv_w, fc2_w, wbf);

  const int B = in_sizes[0] / SEQ;                    // 8192
  fused_kernel<<<B, 512, 0, stream>>>(x, fc1_w, fc1_b, qkv_b, fc2_b, fc3_w, fc3_b,
                                      ln_g, ln_b, wbf, wbf + 384*128, (float*)d_out);
}

// Round 5
// 2876.276 us; speedup vs baseline: 5.0112x; 2.4249x over previous
//
#include <hip/hip_runtime.h>
#include <hip/hip_bf16.h>

#define SEQ 118
#define SAS 136   // sA row stride (elements): 272 B = 17*16 -> b128-aligned, bank-safe

typedef __attribute__((ext_vector_type(8))) short short8;
typedef __attribute__((ext_vector_type(4))) float f32x4;

__device__ __forceinline__ f32x4 mfma16(short8 a, short8 b, f32x4 c){
  return __builtin_amdgcn_mfma_f32_16x16x32_bf16(a, b, c, 0, 0, 0);
}
__device__ __forceinline__ float bfr(float x){            // bf16 RNE round-trip
  return __bfloat162float(__float2bfloat16(x));
}
__device__ __forceinline__ float rsum16(float v){
  v += __shfl_xor(v,1); v += __shfl_xor(v,2); v += __shfl_xor(v,4); v += __shfl_xor(v,8);
  return v;
}
__device__ __forceinline__ float rmax16(float v){
  v = fmaxf(v, __shfl_xor(v,1)); v = fmaxf(v, __shfl_xor(v,2));
  v = fmaxf(v, __shfl_xor(v,4)); v = fmaxf(v, __shfl_xor(v,8));
  return v;
}

__global__ void prep_kernel(const float* __restrict__ qkv_w,
                            const float* __restrict__ fc2_w,
                            __hip_bfloat16* __restrict__ wbf){
  int i = blockIdx.x * 256 + threadIdx.x;   // 65536 total
  if (i < 384*128) wbf[i] = __float2bfloat16(qkv_w[i]);
  else             wbf[i] = __float2bfloat16(fc2_w[i - 384*128]);
}

// VGPR budget is hard-capped at 128 (3 rounds of occupancy attributes: no-op).
// Strategy: make every phase's live set fit under 128.
//  - QKV q-pair and k-pair split into separate loops (halves acc + B-frags)
//  - attention: uniform control flow, all 8 tiles computed, mask via -1e9
//  - FC2: running sums in the t-loop; fc2 outputs stashed f32 in LDS (fXX
//    overlays sK/sVt, dead after attention) -> no xx[8] live range
__global__ __attribute__((amdgpu_flat_work_group_size(512, 512),
                          amdgpu_waves_per_eu(1, 2)))
void fused_kernel(const float* __restrict__ x,
                             const float* __restrict__ fc1_w, const float* __restrict__ fc1_b,
                             const float* __restrict__ qkv_b,
                             const float* __restrict__ fc2_b, const float* __restrict__ fc3_w,
                             const float* __restrict__ fc3_b,
                             const float* __restrict__ ln_g,  const float* __restrict__ ln_b,
                             const __hip_bfloat16* __restrict__ wqkv,   // [384][128] bf16
                             const __hip_bfloat16* __restrict__ wfc2,   // [128][128] bf16
                             float* __restrict__ out)
{
  // LDS pool: sA 34816 | sQ 32768 | sK 32768 | sVt 32768 | sO1 512 | sCb 3584
  // fXX (f32, 64 KB) overlays sK+sVt during the FC2 epilogue.
  __shared__ __align__(16) char smem[137216];
  __hip_bfloat16* sA  = (__hip_bfloat16*)(smem);
  __hip_bfloat16* sQ  = (__hip_bfloat16*)(smem + 34816);
  __hip_bfloat16* sK  = (__hip_bfloat16*)(smem + 67584);
  __hip_bfloat16* sVt = (__hip_bfloat16*)(smem + 100352);
  float*          fXX = (float*)        (smem + 67584);
  float*          sO1 = (float*)        (smem + 133120);
  float*          sCb = (float*)        (smem + 133632);

  const int b    = blockIdx.x;
  const int tid  = threadIdx.x;
  const int wv   = tid >> 6;        // wave 0..7 -> 16-row strip
  const int lane = tid & 63;
  const int c    = lane & 15;
  const int quad = lane >> 4;

  for (int i = tid; i < 896; i += 512){
    float v;
    if      (i < 384) v = qkv_b[i];
    else if (i < 512) v = fc2_b[i-384];
    else if (i < 640) v = fc3_w[i-512];
    else if (i < 768) v = ln_g [i-640];
    else              v = ln_b [i-768];
    sCb[i] = v;
  }
  { // h = silu(x*fc1_w + fc1_b); padded rows (s>=118) zeroed
    int s  = tid >> 2;
    int d0 = (tid & 3) * 32;
    float xs = (s < SEQ) ? x[b*SEQ + s] : 0.f;
    #pragma unroll 8
    for (int i = 0; i < 32; i++){
      int d = d0 + i;
      float v = 0.f;
      if (s < SEQ){
        float z = xs * fc1_w[d] + fc1_b[d];
        v = z / (1.f + __expf(-z));
      }
      sA[s*SAS + d] = __float2bfloat16(v);
    }
  }
  __syncthreads();

  const float* sQB = sCb;
  const float* sFB = sCb + 384;
  const float* sW3 = sCb + 512;
  const float* sLG = sCb + 640;
  const float* sLB = sCb + 768;

  #pragma unroll 1
  for (int p = 0; p < 2; ++p){
    // ================= QKV GEMM (M-strip per wave) =================
    short8 afr[4];
    #pragma unroll
    for (int k4 = 0; k4 < 4; k4++)
      afr[k4] = *(const short8*)(sA + (wv*16 + c)*SAS + k4*32 + quad*8);

    // Q tile-pairs (d, d+64) with RoPE epilogue
    #pragma unroll 1
    for (int t = 0; t < 4; ++t){
      const int d0 = t*16 + c;                      // 0..63
      f32x4 a0={0,0,0,0}, a1={0,0,0,0};
      #pragma unroll
      for (int k4 = 0; k4 < 4; k4++){
        const __hip_bfloat16* wp = wqkv + k4*32 + quad*8;
        short8 b0 = *(const short8*)(wp + (d0     )*128);
        short8 b1 = *(const short8*)(wp + (d0 + 64)*128);
        a0 = mfma16(afr[k4], b0, a0);
        a1 = mfma16(afr[k4], b1, a1);
      }
      float bb0 = sQB[d0], bb1 = sQB[d0+64];
      float invf = exp2f((float)d0 * (-13.287712379549449f/64.f)); // 10000^(-d0/64)
      int hh = d0 & 3, dh = d0 >> 2;
      __hip_bfloat16* q_p = sQ + hh*4096;
      #pragma unroll
      for (int j = 0; j < 4; j++){
        int s = wv*16 + quad*4 + j;
        float ang = (float)s * invf;
        float cv = bfr(__cosf(ang));
        float sv = bfr(__sinf(ang));
        float q1 = a0[j] + bb0, q2 = a1[j] + bb1;
        q_p[s*32 + dh     ] = __float2bfloat16( q1*cv + q2*sv);
        q_p[s*32 + dh + 16] = __float2bfloat16(-q1*sv + q2*cv);
      }
    }
    // K tile-pairs with RoPE epilogue
    #pragma unroll 1
    for (int t = 0; t < 4; ++t){
      const int d0 = t*16 + c;                      // 0..63
      f32x4 a0={0,0,0,0}, a1={0,0,0,0};
      #pragma unroll
      for (int k4 = 0; k4 < 4; k4++){
        const __hip_bfloat16* wp = wqkv + 128*128 + k4*32 + quad*8;
        short8 b0 = *(const short8*)(wp + (d0     )*128);
        short8 b1 = *(const short8*)(wp + (d0 + 64)*128);
        a0 = mfma16(afr[k4], b0, a0);
        a1 = mfma16(afr[k4], b1, a1);
      }
      float bb0 = sQB[128+d0], bb1 = sQB[192+d0];
      float invf = exp2f((float)d0 * (-13.287712379549449f/64.f));
      int hh = d0 & 3, dh = d0 >> 2;
      __hip_bfloat16* k_p = sK + hh*4096;
      #pragma unroll
      for (int j = 0; j < 4; j++){
        int s = wv*16 + quad*4 + j;
        float ang = (float)s * invf;
        float cv = bfr(__cosf(ang));
        float sv = bfr(__sinf(ang));
        float k1 = a0[j] + bb0, k2 = a1[j] + bb1;
        k_p[s*32 + dh     ] = __float2bfloat16( k1*cv + k2*sv);
        k_p[s*32 + dh + 16] = __float2bfloat16(-k1*sv + k2*cv);
      }
    }
    // V tiles -> transposed store sVt[h][dh][s]
    #pragma unroll 1
    for (int t = 0; t < 8; ++t){
      const int d0 = t*16 + c;                      // 0..127
      f32x4 av = {0,0,0,0};
      #pragma unroll
      for (int k4 = 0; k4 < 4; k4++){
        short8 bv = *(const short8*)(wqkv + (256 + d0)*128 + k4*32 + quad*8);
        av = mfma16(afr[k4], bv, av);
      }
      float bias = sQB[256 + d0];
      int hh = d0 & 3, dh = d0 >> 2;
      __hip_bfloat16* vp = sVt + hh*4096 + dh*128 + wv*16 + quad*4;
      #pragma unroll
      for (int j = 0; j < 4; j++) vp[j] = __float2bfloat16(av[j] + bias);
    }
    __syncthreads();   // Q/K/Vt visible to all waves

    // ================= attention (uniform control flow) =================
    #pragma unroll 1
    for (int h = 0; h < 4; ++h){
      const int st = (h & 1) ? (7 - wv) : wv;       // balanced causal strips
      short8 aq = *(const short8*)(sQ + h*4096 + (st*16 + c)*32 + quad*8);
      f32x4 sc[8];
      #pragma unroll
      for (int t = 0; t < 8; ++t){
        short8 bk = *(const short8*)(sK + h*4096 + (t*16 + c)*32 + quad*8);
        f32x4 z = {0,0,0,0};
        sc[t] = mfma16(aq, bk, z);
      }
      const float scale = 0.17677669529663687f;     // 1/sqrt(32)
      #pragma unroll
      for (int j = 0; j < 4; j++){
        const int s = st*16 + quad*4 + j;
        float mx = -3.0e38f;
        #pragma unroll
        for (int t = 0; t < 8; t++){
          float v = ((t*16 + c) <= s) ? sc[t][j]*scale : -1.0e9f;
          sc[t][j] = v;
          mx = fmaxf(mx, v);
        }
        mx = rmax16(mx);
        float sum = 0.f;
        #pragma unroll
        for (int t = 0; t < 8; t++){
          float e = __expf(sc[t][j] - mx);   // masked -> exp(-1e9-mx) = 0
          sc[t][j] = e;
          sum += e;
        }
        sum = rsum16(sum);
        float r = 1.f / sum;
        #pragma unroll
        for (int t = 0; t < 8; t++)
          sA[(wv*16 + quad*4 + j)*SAS + t*16 + c] = __float2bfloat16(sc[t][j]*r);
      }
      // P @ V  (P rows indexed by WAVE -> race-free across heads)
      f32x4 y0 = {0,0,0,0}, y1 = {0,0,0,0};
      #pragma unroll
      for (int kk = 0; kk < 4; kk++){
        short8 ap  = *(const short8*)(sA  + (wv*16 + c)*SAS + kk*32 + quad*8);
        short8 bv0 = *(const short8*)(sVt + h*4096 + (c     )*128 + kk*32 + quad*8);
        short8 bv1 = *(const short8*)(sVt + h*4096 + (16 + c)*128 + kk*32 + quad*8);
        y0 = mfma16(ap, bv0, y0);
        y1 = mfma16(ap, bv1, y1);
      }
      #pragma unroll
      for (int j = 0; j < 4; j++){
        int s = st*16 + quad*4 + j;
        sQ[h*4096 + s*32 + c     ] = __float2bfloat16(y0[j]);   // Y overwrites Q
        sQ[h*4096 + s*32 + 16 + c] = __float2bfloat16(y1[j]);
      }
    }
    __syncthreads();   // Y strips complete; also: done reading sK/sVt (fXX overlay)

    // ================= FC2 + fused epilogue =================
    short8 ay[4];
    #pragma unroll
    for (int k4 = 0; k4 < 4; k4++)
      ay[k4] = *(const short8*)(sQ + k4*4096 + (wv*16 + c)*32 + quad*8);
    f32x4 S1 = {0,0,0,0}, S2 = {0,0,0,0}, S3 = {0,0,0,0};
    #pragma unroll 1
    for (int t = 0; t < 8; t++){
      f32x4 acc = {0,0,0,0};
      #pragma unroll
      for (int k4 = 0; k4 < 4; k4++){
        short8 bw = *(const short8*)(wfc2 + (t*16 + c)*128 + k4*32 + quad*8);
        acc = mfma16(ay[k4], bw, acc);
      }
      float bias = sFB[t*16 + c];
      float w3   = sW3[t*16 + c];
      #pragma unroll
      for (int j = 0; j < 4; j++){
        float z = acc[j] + bias;
        float v = z / (1.f + __expf(-z));           // silu
        fXX[(wv*16 + quad*4 + j)*128 + t*16 + c] = v;   // wave-private rows
        S1[j] += v; S2[j] += v*v; S3[j] += v*w3;
      }
    }
    #pragma unroll
    for (int j = 0; j < 4; j++){
      float s1 = rsum16(S1[j]), s2 = rsum16(S2[j]), s3 = rsum16(S3[j]);
      const int s = wv*16 + quad*4 + j;
      if (p == 0){
        float mu  = s1 * (1.f/128.f);
        float var = fmaxf(s2 * (1.f/128.f) - mu*mu, 0.f);  // clamp: NaN guard
        float rs  = rsqrtf(var + 1e-5f);
        #pragma unroll
        for (int t = 0; t < 8; t++){
          int d = t*16 + c;
          float v = fXX[s*128 + d];
          sA[s*SAS + d] = __float2bfloat16((v - mu)*rs*sLG[d] + sLB[d]);
        }
        if (c == 0) sO1[s] = s3;                    // x1 . fc3_w  (residual readout)
      } else {
        if (c == 0 && s < SEQ) out[b*SEQ + s] = sO1[s] + s3 + fc3_b[0];
      }
    }
    __syncthreads();   // fXX (overlay on sK/sVt) fully consumed before next pass
  }
}

extern "C" void kernel_launch(void* const* d_in, const int* in_sizes, int n_in,
                              void* d_out, int out_size, void* d_ws, size_t ws_size,
                              hipStream_t stream){
  const float* x     = (const float*)d_in[0];
  const float* fc1_w = (const float*)d_in[1];
  const float* fc1_b = (const float*)d_in[2];
  const float* qkv_w = (const float*)d_in[3];
  const float* qkv_b = (const float*)d_in[4];
  const float* fc2_w = (const float*)d_in[5];
  const float* fc2_b = (const float*)d_in[6];
  const float* fc3_w = (const float*)d_in[7];
  const float* fc3_b = (const float*)d_in[8];
  const float* ln_g  = (const float*)d_in[9];
  const float* ln_b  = (const float*)d_in[10];

  __hip_bfloat16* wbf = (__hip_bfloat16*)d_ws;        // 384*128 + 128*128 bf16
  prep_kernel<<<256, 256, 0, stream>>>(qkv_w, fc2_w, wbf);

  const int B = in_sizes[0] / SEQ;                    // 8192
  fused_kernel<<<B, 512, 0, stream>>>(x, fc1_w, fc1_b, qkv_b, fc2_b, fc3_w, fc3_b,
                                      ln_g, ln_b, wbf, wbf + 384*128, (float*)d_out);
}

// Round 7
// 2812.038 us; speedup vs baseline: 5.1257x; 1.0228x over previous
//
#include <hip/hip_runtime.h>
#include <hip/hip_bf16.h>

#define SEQ 118
#define SAS 136   // sA stride (272 B): frag reads 8-cy minimal
#define SQS 40    // sQ/sK stride (80 B): frag reads + packed writes conflict-free
#define SVS 136   // sVt stride (272 B): PV B-frag reads conflict-free (was 16-way at 128)
#define SPS 40    // sP stride

typedef __attribute__((ext_vector_type(8))) short short8;
typedef __attribute__((ext_vector_type(4))) float f32x4;

__device__ __forceinline__ f32x4 mfma16(short8 a, short8 b, f32x4 c){
  return __builtin_amdgcn_mfma_f32_16x16x32_bf16(a, b, c, 0, 0, 0);
}
__device__ __forceinline__ float bfr(float x){            // bf16 RNE round-trip
  return __bfloat162float(__float2bfloat16(x));
}
__device__ __forceinline__ float rsum16(float v){
  v += __shfl_xor(v,1); v += __shfl_xor(v,2); v += __shfl_xor(v,4); v += __shfl_xor(v,8);
  return v;
}
__device__ __forceinline__ float rmax16(float v){
  v = fmaxf(v, __shfl_xor(v,1)); v = fmaxf(v, __shfl_xor(v,2));
  v = fmaxf(v, __shfl_xor(v,4)); v = fmaxf(v, __shfl_xor(v,8));
  return v;
}
__device__ __forceinline__ unsigned pack_bf2(float lo, float hi){
  unsigned short a = __builtin_bit_cast(unsigned short, __float2bfloat16(lo));
  unsigned short b = __builtin_bit_cast(unsigned short, __float2bfloat16(hi));
  return ((unsigned)b << 16) | (unsigned)a;
}

// Pre-permuted bf16 weights:
//  wq/wk/wv: [h][n=0..31][k=0..127], head-dim n <-> original col d = 4n + h
//            (input-side to_heads: reshape(SEQ,DH,H) -> dim dh picks col 4*dh+h)
//  w2p:      [n][k'], k' = h*32 + r, dh = (r>>1) + (r&1)*16,
//            ORIG k = h*32 + dh   (output-side reshape is HEAD-MAJOR:
//            transpose(y,(0,2,1,3)).reshape -> y_full[s, h*32+dh]).
//            Round 6 bug: used input-side 4*dh+h here -> absmax 0.52.
__global__ void prep_kernel(const float* __restrict__ qkv_w,
                            const float* __restrict__ fc2_w,
                            __hip_bfloat16* __restrict__ wbf){
  int i = blockIdx.x * 256 + threadIdx.x;   // 65536 total
  int seg = i >> 14;
  int r   = i & 16383;
  int row = r >> 7;
  int k   = r & 127;
  float v;
  if (seg < 3){
    int h = row >> 5, n = row & 31;
    v = qkv_w[(seg*128 + 4*n + h)*128 + k];
  } else {
    int h = k >> 5, rr = k & 31;
    int dh = (rr >> 1) + (rr & 1)*16;
    v = fc2_w[row*128 + h*32 + dh];
  }
  wbf[i] = __float2bfloat16(v);
}

// Per-head streaming: LDS 76 KB -> 2 blocks/CU (4 waves/SIMD). The default
// 128-VGPR cap is exactly the 4-waves/EU budget -> no spills by design
// (worst phase ~95 live regs). FC2 accumulates per-head k-slices into
// registers; LN/readout directly from regs (no f32 stash).
__launch_bounds__(512)
__global__ void fused_kernel(const float* __restrict__ x,
                             const float* __restrict__ fc1_w, const float* __restrict__ fc1_b,
                             const float* __restrict__ qkv_b,
                             const float* __restrict__ fc2_b, const float* __restrict__ fc3_w,
                             const float* __restrict__ fc3_b,
                             const float* __restrict__ ln_g,  const float* __restrict__ ln_b,
                             const __hip_bfloat16* __restrict__ wbf,
                             float* __restrict__ out)
{
  __shared__ __align__(16) char smem[77824];
  __hip_bfloat16* sA  = (__hip_bfloat16*)(smem);            // 128 x 136   34816
  __hip_bfloat16* sQ  = (__hip_bfloat16*)(smem + 34816);    // 128 x 40    10240
  __hip_bfloat16* sK  = (__hip_bfloat16*)(smem + 45056);    // 128 x 40    10240
  __hip_bfloat16* sVt = (__hip_bfloat16*)(smem + 55296);    //  32 x 136    8704
  __hip_bfloat16* sP  = (__hip_bfloat16*)(smem + 64000);    // 128 x 40    10240
  float*          sCb = (float*)        (smem + 74240);     // 896 f32      3584

  const __hip_bfloat16* wq  = wbf;
  const __hip_bfloat16* wk  = wbf + 16384;
  const __hip_bfloat16* wvw = wbf + 32768;
  const __hip_bfloat16* w2  = wbf + 49152;

  const int b    = blockIdx.x;
  const int tid  = threadIdx.x;
  const int wv   = tid >> 6;        // wave 0..7 -> 16-row strip
  const int lane = tid & 63;
  const int c    = lane & 15;
  const int quad = lane >> 4;

  for (int i = tid; i < 896; i += 512){
    float v;
    if      (i < 384) v = qkv_b[i];
    else if (i < 512) v = fc2_b[i-384];
    else if (i < 640) v = fc3_w[i-512];
    else if (i < 768) v = ln_g [i-640];
    else              v = ln_b [i-768];
    sCb[i] = v;
  }
  { // h = silu(x*fc1_w + fc1_b); padded rows (s>=118) zeroed; rows are wave-private
    int s  = tid >> 2;
    int d0 = (tid & 3) * 32;
    float xs = (s < SEQ) ? x[b*SEQ + s] : 0.f;
    #pragma unroll 8
    for (int i = 0; i < 32; i++){
      int d = d0 + i;
      float v = 0.f;
      if (s < SEQ){
        float z = xs * fc1_w[d] + fc1_b[d];
        v = z / (1.f + __expf(-z));
      }
      sA[s*SAS + d] = __float2bfloat16(v);
    }
  }
  __syncthreads();

  const float* sQB = sCb;
  const float* sFB = sCb + 384;
  const float* sW3 = sCb + 512;
  const float* sLG = sCb + 640;
  const float* sLB = sCb + 768;

  float o1[4];   // pass-0 fc3 readout, carried in regs to pass 1

  #pragma unroll 1
  for (int p = 0; p < 2; ++p){
    f32x4 acc2[8];                     // FC2 accumulators, persist across heads
    #pragma unroll
    for (int t = 0; t < 8; t++) acc2[t] = (f32x4){0.f,0.f,0.f,0.f};

    #pragma unroll 1
    for (int h = 0; h < 4; ++h){
      short8 afr[4];                   // own-strip A fragments (reload/head: cheap)
      #pragma unroll
      for (int k4 = 0; k4 < 4; k4++)
        afr[k4] = *(const short8*)(sA + (wv*16 + c)*SAS + k4*32 + quad*8);

      const float invf = exp2f((float)(4*c + h) * (-13.287712379549449f/64.f));

      { // ---- Q & K head GEMMs + shared RoPE epilogue ----
        const __hip_bfloat16* wpq = wq + (h*32 + c)*128 + quad*8;
        const __hip_bfloat16* wpk = wk + (h*32 + c)*128 + quad*8;
        f32x4 q0={0,0,0,0}, q1={0,0,0,0}, k0={0,0,0,0}, k1={0,0,0,0};
        #pragma unroll
        for (int k4 = 0; k4 < 4; k4++){
          short8 bq0 = *(const short8*)(wpq + k4*32);
          short8 bq1 = *(const short8*)(wpq + 2048 + k4*32);
          short8 bk0 = *(const short8*)(wpk + k4*32);
          short8 bk1 = *(const short8*)(wpk + 2048 + k4*32);
          q0 = mfma16(afr[k4], bq0, q0);
          q1 = mfma16(afr[k4], bq1, q1);
          k0 = mfma16(afr[k4], bk0, k0);
          k1 = mfma16(afr[k4], bk1, k1);
        }
        float bQ0 = sQB[4*c + h],       bQ1 = sQB[4*c + 64 + h];
        float bK0 = sQB[128 + 4*c + h], bK1 = sQB[128 + 4*c + 64 + h];
        #pragma unroll
        for (int j = 0; j < 4; j++){
          int s = wv*16 + quad*4 + j;
          float ang = (float)s * invf;
          float cv = bfr(__cosf(ang)), sv = bfr(__sinf(ang));
          float xq1 = q0[j] + bQ0, xq2 = q1[j] + bQ1;
          float xk1 = k0[j] + bK0, xk2 = k1[j] + bK1;
          // paired (dh, dh+16) layout -> k-order permutation consistent for Q,K
          *(unsigned*)(sQ + s*SQS + 2*c) = pack_bf2( xq1*cv + xq2*sv, -xq1*sv + xq2*cv);
          *(unsigned*)(sK + s*SQS + 2*c) = pack_bf2( xk1*cv + xk2*sv, -xk1*sv + xk2*cv);
        }
      }
      { // ---- V head GEMM -> transposed sVt[dh][s] ----
        const __hip_bfloat16* wpv = wvw + (h*32 + c)*128 + quad*8;
        f32x4 v0={0,0,0,0}, v1={0,0,0,0};
        #pragma unroll
        for (int k4 = 0; k4 < 4; k4++){
          short8 b0 = *(const short8*)(wpv + k4*32);
          short8 b1 = *(const short8*)(wpv + 2048 + k4*32);
          v0 = mfma16(afr[k4], b0, v0);
          v1 = mfma16(afr[k4], b1, v1);
        }
        float bV0 = sQB[256 + 4*c + h], bV1 = sQB[256 + 4*c + 64 + h];
        int s0 = wv*16 + quad*4;
        *(unsigned*)(sVt + (c   )*SVS + s0    ) = pack_bf2(v0[0]+bV0, v0[1]+bV0);
        *(unsigned*)(sVt + (c   )*SVS + s0 + 2) = pack_bf2(v0[2]+bV0, v0[3]+bV0);
        *(unsigned*)(sVt + (c+16)*SVS + s0    ) = pack_bf2(v1[0]+bV1, v1[1]+bV1);
        *(unsigned*)(sVt + (c+16)*SVS + s0 + 2) = pack_bf2(v1[2]+bV1, v1[3]+bV1);
      }
      __syncthreads();   // K rows + Vt cols read cross-wave below

      // ---- QK^T (causal tile skip, wave-uniform) + softmax ----
      short8 aq = *(const short8*)(sQ + (wv*16 + c)*SQS + quad*8);
      f32x4 sc[8];
      #pragma unroll
      for (int t = 0; t < 8; t++){
        sc[t] = (f32x4){0.f,0.f,0.f,0.f};
        if (t <= wv){
          short8 bk = *(const short8*)(sK + (t*16 + c)*SQS + quad*8);
          f32x4 z = {0,0,0,0};
          sc[t] = mfma16(aq, bk, z);
        }
      }
      const float scale = 0.17677669529663687f;   // 1/sqrt(32)
      #pragma unroll
      for (int j = 0; j < 4; j++){
        int s = wv*16 + quad*4 + j;
        float mx = -3.0e38f;
        #pragma unroll
        for (int t = 0; t < 8; t++) if (t <= wv){
          float v = ((t*16 + c) <= s) ? sc[t][j]*scale : -1.0e9f;
          sc[t][j] = v; mx = fmaxf(mx, v);
        }
        mx = rmax16(mx);
        float sum = 0.f;
        #pragma unroll
        for (int t = 0; t < 8; t++) if (t <= wv){
          float e = __expf(sc[t][j] - mx); sc[t][j] = e; sum += e;
        }
        sum = rsum16(sum);
        float r = 1.f / sum;
        #pragma unroll
        for (int t = 0; t < 8; t++) if (t <= wv) sc[t][j] *= r;
      }

      // ---- P@V in 32-k quarters through sP (wave-private, no barrier) ----
      f32x4 y0 = {0,0,0,0}, y1 = {0,0,0,0};
      auto pv_quarter = [&](int qt, f32x4 pa, f32x4 pb){
        int s0 = wv*16 + quad*4;
        #pragma unroll
        for (int j = 0; j < 4; j++){
          sP[(s0+j)*SPS + c     ] = __float2bfloat16(pa[j]);
          sP[(s0+j)*SPS + 16 + c] = __float2bfloat16(pb[j]);
        }
        short8 ap  = *(const short8*)(sP + (wv*16 + c)*SPS + quad*8);
        short8 bv0 = *(const short8*)(sVt + (c   )*SVS + qt*32 + quad*8);
        short8 bv1 = *(const short8*)(sVt + (c+16)*SVS + qt*32 + quad*8);
        y0 = mfma16(ap, bv0, y0);
        y1 = mfma16(ap, bv1, y1);
      };
      int qmax = wv >> 1;                    // quarters at/below the diagonal
      pv_quarter(0, sc[0], sc[1]);
      if (qmax >= 1) pv_quarter(1, sc[2], sc[3]);
      if (qmax >= 2) pv_quarter(2, sc[4], sc[5]);
      if (qmax >= 3) pv_quarter(3, sc[6], sc[7]);

      // ---- Y -> sP (k'-paired), FC2 partial over this head's k-slice ----
      {
        int s0 = wv*16 + quad*4;
        #pragma unroll
        for (int j = 0; j < 4; j++)
          *(unsigned*)(sP + (s0+j)*SPS + 2*c) = pack_bf2(y0[j], y1[j]);
      }
      short8 ayh = *(const short8*)(sP + (wv*16 + c)*SPS + quad*8);
      #pragma unroll
      for (int t = 0; t < 8; t++){
        short8 bw = *(const short8*)(w2 + (t*16 + c)*128 + h*32 + quad*8);
        acc2[t] = mfma16(ayh, bw, acc2[t]);
      }
      __syncthreads();   // protect sQ/sK/sVt before next head overwrites
    }

    // ================= epilogue: silu + LN / readout, all from regs =======
    f32x4 S1 = {0,0,0,0}, S2 = {0,0,0,0}, S3 = {0,0,0,0};
    #pragma unroll
    for (int t = 0; t < 8; t++){
      float bias = sFB[t*16 + c];
      float w3   = sW3[t*16 + c];
      #pragma unroll
      for (int j = 0; j < 4; j++){
        float z = acc2[t][j] + bias;
        float v = z / (1.f + __expf(-z));   // silu
        acc2[t][j] = v;
        S1[j] += v; S2[j] += v*v; S3[j] += v*w3;
      }
    }
    #pragma unroll
    for (int j = 0; j < 4; j++){
      float s1 = rsum16(S1[j]), s2 = rsum16(S2[j]), s3 = rsum16(S3[j]);
      int s = wv*16 + quad*4 + j;
      if (p == 0){
        float mu  = s1 * (1.f/128.f);
        float var = fmaxf(s2 * (1.f/128.f) - mu*mu, 0.f);   // NaN guard (pad rows)
        float rs  = rsqrtf(var + 1e-5f);
        #pragma unroll
        for (int t = 0; t < 8; t++){
          int d = t*16 + c;
          sA[s*SAS + d] = __float2bfloat16((acc2[t][j] - mu)*rs*sLG[d] + sLB[d]);
        }
        o1[j] = s3;                        // x1 . fc3_w residual readout
      } else {
        if (c == 0 && s < SEQ) out[b*SEQ + s] = o1[j] + s3 + fc3_b[0];
      }
    }
    // no inter-pass barrier needed: sA writes/reads are wave-private rows;
    // sQ/sK/sVt protected by the last head's trailing barrier
  }
}

extern "C" void kernel_launch(void* const* d_in, const int* in_sizes, int n_in,
                              void* d_out, int out_size, void* d_ws, size_t ws_size,
                              hipStream_t stream){
  const float* x     = (const float*)d_in[0];
  const float* fc1_w = (const float*)d_in[1];
  const float* fc1_b = (const float*)d_in[2];
  const float* qkv_w = (const float*)d_in[3];
  const float* qkv_b = (const float*)d_in[4];
  const float* fc2_w = (const float*)d_in[5];
  const float* fc2_b = (const float*)d_in[6];
  const float* fc3_w = (const float*)d_in[7];
  const float* fc3_b = (const float*)d_in[8];
  const float* ln_g  = (const float*)d_in[9];
  const float* ln_b  = (const float*)d_in[10];

  __hip_bfloat16* wbf = (__hip_bfloat16*)d_ws;   // 65536 bf16 = 128 KB
  prep_kernel<<<256, 256, 0, stream>>>(qkv_w, fc2_w, wbf);

  const int B = in_sizes[0] / SEQ;               // 8192
  fused_kernel<<<B, 512, 0, stream>>>(x, fc1_w, fc1_b, qkv_b, fc2_b, fc3_w, fc3_b,
                                      ln_g, ln_b, wbf, (float*)d_out);
}

// Round 8
// 2538.874 us; speedup vs baseline: 5.6772x; 1.1076x over previous
//
#include <hip/hip_runtime.h>
#include <hip/hip_bf16.h>

#define SEQ 118
#define YS  136   // Ybuf stride (272 B, 16B-aligned rows, bank-spread verified)
#define SQS 40    // sQP/sK stride (80 B)
#define SVS 136   // sVt stride

typedef __attribute__((ext_vector_type(8))) short short8;
typedef __attribute__((ext_vector_type(4))) float f32x4;

__device__ __forceinline__ f32x4 mfma16(short8 a, short8 b, f32x4 c){
  return __builtin_amdgcn_mfma_f32_16x16x32_bf16(a, b, c, 0, 0, 0);
}
__device__ __forceinline__ float bfr(float x){
  return __bfloat162float(__float2bfloat16(x));
}
__device__ __forceinline__ float rsum16(float v){
  v += __shfl_xor(v,1); v += __shfl_xor(v,2); v += __shfl_xor(v,4); v += __shfl_xor(v,8);
  return v;
}
__device__ __forceinline__ float rmax16(float v){
  v = fmaxf(v, __shfl_xor(v,1)); v = fmaxf(v, __shfl_xor(v,2));
  v = fmaxf(v, __shfl_xor(v,4)); v = fmaxf(v, __shfl_xor(v,8));
  return v;
}
__device__ __forceinline__ unsigned pack_bf2(float lo, float hi){
  unsigned short a = __builtin_bit_cast(unsigned short, __float2bfloat16(lo));
  unsigned short b = __builtin_bit_cast(unsigned short, __float2bfloat16(hi));
  return ((unsigned)b << 16) | (unsigned)a;
}

// Pre-permuted bf16 weights (verified in round 7):
//  wq/wk/wv: [h][n][k], n <-> orig col d = 4n + h (input-side to_heads)
//  w2:       [n][k'], k' = h*32 + r, dh = (r>>1)+(r&1)*16, orig k = h*32 + dh
__global__ void prep_kernel(const float* __restrict__ qkv_w,
                            const float* __restrict__ fc2_w,
                            __hip_bfloat16* __restrict__ wbf){
  int i = blockIdx.x * 256 + threadIdx.x;   // 65536 total
  int seg = i >> 14;
  int r   = i & 16383;
  int row = r >> 7;
  int k   = r & 127;
  float v;
  if (seg < 3){
    int h = row >> 5, n = row & 31;
    v = qkv_w[(seg*128 + 4*n + h)*128 + k];
  } else {
    int h = k >> 5, rr = k & 31;
    int dh = (rr >> 1) + (rr & 1)*16;
    v = fc2_w[row*128 + h*32 + dh];
  }
  wbf[i] = __float2bfloat16(v);
}

// Register-diet + <64KB LDS version. gfx950 unified VGPR/AGPR file: prior
// rounds' persistent acc2[8] + sc[8] pushed TOTAL regs past 128 -> 3 waves/EU
// -> 1 block/CU forever (occupancy pinned at 24%). Now: persistent state is
// only afr[4]+o1[4]; FC2 runs once per pass from Ybuf; LDS 63328 B -> 2
// blocks/CU by both LDS and (intended) registers.
__launch_bounds__(512, 4)
__global__ void fused_kernel(const float* __restrict__ x,
                             const float* __restrict__ fc1_w, const float* __restrict__ fc1_b,
                             const float* __restrict__ qkv_b,
                             const float* __restrict__ fc2_b, const float* __restrict__ fc3_w,
                             const float* __restrict__ fc3_b,
                             const float* __restrict__ ln_g,  const float* __restrict__ ln_b,
                             const __hip_bfloat16* __restrict__ wbf,
                             float* __restrict__ out)
{
  __shared__ __align__(16) char smem[63328];
  __hip_bfloat16* Ybuf = (__hip_bfloat16*)(smem);           // 118 x 136  32096
  __hip_bfloat16* sQP  = (__hip_bfloat16*)(smem + 32096);   // 128 x 40   10240 (Q then P, wave-private)
  __hip_bfloat16* sK   = (__hip_bfloat16*)(smem + 42336);   // 128 x 40   10240
  __hip_bfloat16* sVt  = (__hip_bfloat16*)(smem + 52576);   //  32 x 136   8704
  float*          sCb  = (float*)        (smem + 61280);    // 512 f32     2048

  const __hip_bfloat16* wq  = wbf;
  const __hip_bfloat16* wk  = wbf + 16384;
  const __hip_bfloat16* wvw = wbf + 32768;
  const __hip_bfloat16* w2  = wbf + 49152;

  const int b    = blockIdx.x;
  const int tid  = threadIdx.x;
  const int wv   = tid >> 6;        // wave 0..7 -> 16-row strip
  const int lane = tid & 63;
  const int c    = lane & 15;
  const int quad = lane >> 4;
  const int arow = wv*16 + c;       // this lane's M-row for A/ay fragments

  { // sCb: fc2_b(0..127) fc3_w(128..255) ln_g(256..383) ln_b(384..511)
    int i = tid;
    if (i < 512){
      float v;
      if      (i < 128) v = fc2_b[i];
      else if (i < 256) v = fc3_w[i-128];
      else if (i < 384) v = ln_g [i-256];
      else              v = ln_b [i-384];
      sCb[i] = v;
    }
  }
  __syncthreads();

  float o1[4];

  #pragma unroll 1
  for (int p = 0; p < 2; ++p){
    // ---- A fragments for this pass (registers only) ----
    short8 afr[4];
    if (p == 0){
      float xs = (arow < SEQ) ? x[b*SEQ + arow] : 0.f;
      #pragma unroll
      for (int k4 = 0; k4 < 4; k4++){
        int d0 = k4*32 + quad*8;
        short8 fr;
        #pragma unroll
        for (int i = 0; i < 8; i++){
          float z = xs * fc1_w[d0+i] + fc1_b[d0+i];
          float v = z / (1.f + __expf(-z));
          if (arow >= SEQ) v = 0.f;             // pad rows exact zero
          fr[i] = (short)__builtin_bit_cast(unsigned short, __float2bfloat16(v));
        }
        afr[k4] = fr;
      }
    } else {
      #pragma unroll
      for (int k4 = 0; k4 < 4; k4++){
        short8 fr = *(const short8*)(Ybuf + arow*YS + k4*32 + quad*8);
        if (arow >= SEQ) fr = (short8){0,0,0,0,0,0,0,0};  // NaN guard for V path
        afr[k4] = fr;
      }
    }

    #pragma unroll 1
    for (int h = 0; h < 4; ++h){
      const float invf = exp2f((float)(4*c + h) * (-0.20762050593045f)); // 10000^(-d/64)

      { // ---- Q & K head GEMMs + RoPE -> sQP / sK (packed pair k-order) ----
        const __hip_bfloat16* wpq = wq + (h*32 + c)*128 + quad*8;
        const __hip_bfloat16* wpk = wk + (h*32 + c)*128 + quad*8;
        f32x4 q0={0,0,0,0}, q1={0,0,0,0}, k0={0,0,0,0}, k1={0,0,0,0};
        #pragma unroll
        for (int k4 = 0; k4 < 4; k4++){
          short8 bq0 = *(const short8*)(wpq + k4*32);
          short8 bq1 = *(const short8*)(wpq + 2048 + k4*32);
          short8 bk0 = *(const short8*)(wpk + k4*32);
          short8 bk1 = *(const short8*)(wpk + 2048 + k4*32);
          q0 = mfma16(afr[k4], bq0, q0);
          q1 = mfma16(afr[k4], bq1, q1);
          k0 = mfma16(afr[k4], bk0, k0);
          k1 = mfma16(afr[k4], bk1, k1);
        }
        float bQ0 = qkv_b[      4*c + h], bQ1 = qkv_b[ 64 + 4*c + h];
        float bK0 = qkv_b[128 + 4*c + h], bK1 = qkv_b[192 + 4*c + h];
        #pragma unroll
        for (int j = 0; j < 4; j++){
          int s = wv*16 + quad*4 + j;
          float ang = (float)s * invf;
          float cv = bfr(__cosf(ang)), sv = bfr(__sinf(ang));
          float xq1 = q0[j] + bQ0, xq2 = q1[j] + bQ1;
          float xk1 = k0[j] + bK0, xk2 = k1[j] + bK1;
          *(unsigned*)(sQP + s*SQS + 2*c) = pack_bf2( xq1*cv + xq2*sv, -xq1*sv + xq2*cv);
          *(unsigned*)(sK  + s*SQS + 2*c) = pack_bf2( xk1*cv + xk2*sv, -xk1*sv + xk2*cv);
        }
      }
      { // ---- V head GEMM -> transposed sVt[dh][s] ----
        const __hip_bfloat16* wpv = wvw + (h*32 + c)*128 + quad*8;
        f32x4 v0={0,0,0,0}, v1={0,0,0,0};
        #pragma unroll
        for (int k4 = 0; k4 < 4; k4++){
          short8 b0 = *(const short8*)(wpv + k4*32);
          short8 b1 = *(const short8*)(wpv + 2048 + k4*32);
          v0 = mfma16(afr[k4], b0, v0);
          v1 = mfma16(afr[k4], b1, v1);
        }
        float bV0 = qkv_b[256 + 4*c + h], bV1 = qkv_b[320 + 4*c + h];
        int s0 = wv*16 + quad*4;
        *(unsigned*)(sVt + (c   )*SVS + s0    ) = pack_bf2(v0[0]+bV0, v0[1]+bV0);
        *(unsigned*)(sVt + (c   )*SVS + s0 + 2) = pack_bf2(v0[2]+bV0, v0[3]+bV0);
        *(unsigned*)(sVt + (c+16)*SVS + s0    ) = pack_bf2(v1[0]+bV1, v1[1]+bV1);
        *(unsigned*)(sVt + (c+16)*SVS + s0 + 2) = pack_bf2(v1[2]+bV1, v1[3]+bV1);
      }
      __syncthreads();   // (B) K/Vt visible to all waves

      // ---- QK^T (causal tile skip) + softmax (exp2-folded) ----
      short8 aq = *(const short8*)(sQP + arow*SQS + quad*8);
      f32x4 sc[8];
      #pragma unroll
      for (int t = 0; t < 8; t++){
        sc[t] = (f32x4){0.f,0.f,0.f,0.f};
        if (t <= wv){
          short8 bk = *(const short8*)(sK + (t*16 + c)*SQS + quad*8);
          f32x4 z = {0,0,0,0};
          sc[t] = mfma16(aq, bk, z);
        }
      }
      const float ksc = 0.25500525502f;   // (1/sqrt(32)) * (1/ln2)
      #pragma unroll
      for (int j = 0; j < 4; j++){
        int s = wv*16 + quad*4 + j;
        float mx = -3.0e38f;
        #pragma unroll
        for (int t = 0; t < 8; t++) if (t <= wv){
          float v = ((t*16 + c) <= s) ? sc[t][j]*ksc : -1.0e9f;
          sc[t][j] = v; mx = fmaxf(mx, v);
        }
        mx = rmax16(mx);
        float sum = 0.f;
        #pragma unroll
        for (int t = 0; t < 8; t++) if (t <= wv){
          float e = exp2f(sc[t][j] - mx); sc[t][j] = e; sum += e;
        }
        sum = rsum16(sum);
        float r = 1.f / sum;
        #pragma unroll
        for (int t = 0; t < 8; t++) if (t <= wv) sc[t][j] *= r;
      }

      // ---- P@V in 32-k quarters through sQP (wave-private; Q is dead) ----
      f32x4 y0 = {0,0,0,0}, y1 = {0,0,0,0};
      auto pv_quarter = [&](int qt, f32x4 pa, f32x4 pb){
        int s0 = wv*16 + quad*4;
        #pragma unroll
        for (int j = 0; j < 4; j++){
          sQP[(s0+j)*SQS + c     ] = __float2bfloat16(pa[j]);
          sQP[(s0+j)*SQS + 16 + c] = __float2bfloat16(pb[j]);
        }
        short8 ap  = *(const short8*)(sQP + arow*SQS + quad*8);
        short8 bv0 = *(const short8*)(sVt + (c   )*SVS + qt*32 + quad*8);
        short8 bv1 = *(const short8*)(sVt + (c+16)*SVS + qt*32 + quad*8);
        y0 = mfma16(ap, bv0, y0);
        y1 = mfma16(ap, bv1, y1);
      };
      int qmax = wv >> 1;
      pv_quarter(0, sc[0], sc[1]);
      if (qmax >= 1) pv_quarter(1, sc[2], sc[3]);
      if (qmax >= 2) pv_quarter(2, sc[4], sc[5]);
      if (qmax >= 3) pv_quarter(3, sc[6], sc[7]);

      { // ---- Y -> Ybuf at this head's k'-slice (guarded: 118 rows only) ----
        int s0 = wv*16 + quad*4;
        #pragma unroll
        for (int j = 0; j < 4; j++)
          if (s0 + j < SEQ)
            *(unsigned*)(Ybuf + (s0+j)*YS + h*32 + 2*c) = pack_bf2(y0[j], y1[j]);
      }
      __syncthreads();   // (D) all reads of K/Vt done; also fences Ybuf for FC2
    }

    // ================= FC2 (once per pass) + silu + LN / readout ==========
    short8 ay[4];
    #pragma unroll
    for (int k4 = 0; k4 < 4; k4++)
      ay[k4] = *(const short8*)(Ybuf + arow*YS + k4*32 + quad*8);  // pad rows: aliased garbage, row-confined
    f32x4 xx[8];
    f32x4 S1 = {0,0,0,0}, S2 = {0,0,0,0}, S3 = {0,0,0,0};
    #pragma unroll 1
    for (int t = 0; t < 8; t++){
      f32x4 acc = {0,0,0,0};
      #pragma unroll
      for (int k4 = 0; k4 < 4; k4++){
        short8 bw = *(const short8*)(w2 + (t*16 + c)*128 + k4*32 + quad*8);
        acc = mfma16(ay[k4], bw, acc);
      }
      float bias = sCb[t*16 + c];
      float w3   = sCb[128 + t*16 + c];
      #pragma unroll
      for (int j = 0; j < 4; j++){
        float z = acc[j] + bias;
        float v = z / (1.f + __expf(-z));   // silu
        xx[t][j] = v;
        S1[j] += v; S2[j] += v*v; S3[j] += v*w3;
      }
    }
    #pragma unroll
    for (int j = 0; j < 4; j++){
      float s1 = rsum16(S1[j]), s2 = rsum16(S2[j]), s3 = rsum16(S3[j]);
      int s = wv*16 + quad*4 + j;
      if (p == 0){
        float mu  = s1 * (1.f/128.f);
        float var = fmaxf(s2 * (1.f/128.f) - mu*mu, 0.f);
        float rs  = rsqrtf(var + 1e-5f);
        if (s < SEQ){
          #pragma unroll
          for (int t = 0; t < 8; t++){
            int d = t*16 + c;
            Ybuf[s*YS + d] = __float2bfloat16((xx[t][j] - mu)*rs*sCb[256+d] + sCb[384+d]);
          }
        }
        o1[j] = s3;                        // x1 . fc3_w residual readout
      } else {
        if (c == 0 && s < SEQ) out[b*SEQ + s] = o1[j] + s3 + fc3_b[0];
      }
    }
    if (p == 0) __syncthreads();   // fence LN writes before pass-1 afr reads
  }
}

extern "C" void kernel_launch(void* const* d_in, const int* in_sizes, int n_in,
                              void* d_out, int out_size, void* d_ws, size_t ws_size,
                              hipStream_t stream){
  const float* x     = (const float*)d_in[0];
  const float* fc1_w = (const float*)d_in[1];
  const float* fc1_b = (const float*)d_in[2];
  const float* qkv_w = (const float*)d_in[3];
  const float* qkv_b = (const float*)d_in[4];
  const float* fc2_w = (const float*)d_in[5];
  const float* fc2_b = (const float*)d_in[6];
  const float* fc3_w = (const float*)d_in[7];
  const float* fc3_b = (const float*)d_in[8];
  const float* ln_g  = (const float*)d_in[9];
  const float* ln_b  = (const float*)d_in[10];

  __hip_bfloat16* wbf = (__hip_bfloat16*)d_ws;   // 65536 bf16 = 128 KB
  prep_kernel<<<256, 256, 0, stream>>>(qkv_w, fc2_w, wbf);

  const int B = in_sizes[0] / SEQ;               // 8192
  fused_kernel<<<B, 512, 0, stream>>>(x, fc1_w, fc1_b, qkv_b, fc2_b, fc3_w, fc3_b,
                                      ln_g, ln_b, wbf, (float*)d_out);
}

// Round 10
// 2521.285 us; speedup vs baseline: 5.7168x; 1.0070x over previous
//
#include <hip/hip_runtime.h>
#include <hip/hip_bf16.h>

#define SEQ 118
#define YS  136   // Ybuf stride (272 B, 16B-aligned rows)
#define SQS 40    // sQP/sK stride (80 B)
#define SVS 136   // sVt stride

typedef __attribute__((ext_vector_type(8))) short short8;
typedef __attribute__((ext_vector_type(4))) float f32x4;

__device__ __forceinline__ f32x4 mfma16(short8 a, short8 b, f32x4 c){
  return __builtin_amdgcn_mfma_f32_16x16x32_bf16(a, b, c, 0, 0, 0);
}
__device__ __forceinline__ float bfr(float x){
  return __bfloat162float(__float2bfloat16(x));
}
__device__ __forceinline__ float rcpf(float x){ return __builtin_amdgcn_rcpf(x); }
__device__ __forceinline__ float fsilu(float z){   // z*sigmoid(z), rcp+exp2 (1-ulp parts)
  return z * rcpf(1.f + exp2f(-1.442695041f * z));
}
__device__ __forceinline__ float rsum16(float v){
  v += __shfl_xor(v,1); v += __shfl_xor(v,2); v += __shfl_xor(v,4); v += __shfl_xor(v,8);
  return v;
}
__device__ __forceinline__ float rmax16(float v){
  v = fmaxf(v, __shfl_xor(v,1)); v = fmaxf(v, __shfl_xor(v,2));
  v = fmaxf(v, __shfl_xor(v,4)); v = fmaxf(v, __shfl_xor(v,8));
  return v;
}
__device__ __forceinline__ unsigned pack_bf2(float lo, float hi){
  __hip_bfloat162 h2 = __float22bfloat162_rn(float2{lo, hi});  // packed RNE cvt
  unsigned u; __builtin_memcpy(&u, &h2, 4);   // bit_cast rejected: non-trivial copy
  return u;
}

// Pre-permuted bf16 weights (verified round 7):
//  wq/wk/wv: [h][n][k], n <-> orig col d = 4n + h (input-side to_heads)
//  w2:       [n][k'], k' = h*32 + r, dh = (r>>1)+(r&1)*16, orig k = h*32 + dh
__global__ void prep_kernel(const float* __restrict__ qkv_w,
                            const float* __restrict__ fc2_w,
                            __hip_bfloat16* __restrict__ wbf){
  int i = blockIdx.x * 256 + threadIdx.x;   // 65536 total
  int seg = i >> 14;
  int r   = i & 16383;
  int row = r >> 7;
  int k   = r & 127;
  float v;
  if (seg < 3){
    int h = row >> 5, n = row & 31;
    v = qkv_w[(seg*128 + 4*n + h)*128 + k];
  } else {
    int h = k >> 5, rr = k & 31;
    int dh = (rr >> 1) + (rr & 1)*16;
    v = fc2_w[row*128 + h*32 + dh];
  }
  wbf[i] = __float2bfloat16(v);
}

// Round 10 = round 9 with the bit_cast fixed (memcpy pun).
// VALU diet on the round-8 skeleton (2 blocks/CU, VGPR 64, no spill):
// div->v_rcp everywhere, packed bf16 cvts, Q pre-scaled by 1/sqrt(32)/ln2
// (softmax runs in exp2 domain with no per-score scaling), causal mask only
// on the diagonal tile, softmax normalization deferred onto y (linearity).
__launch_bounds__(512, 4)
__global__ void fused_kernel(const float* __restrict__ x,
                             const float* __restrict__ fc1_w, const float* __restrict__ fc1_b,
                             const float* __restrict__ qkv_b,
                             const float* __restrict__ fc2_b, const float* __restrict__ fc3_w,
                             const float* __restrict__ fc3_b,
                             const float* __restrict__ ln_g,  const float* __restrict__ ln_b,
                             const __hip_bfloat16* __restrict__ wbf,
                             float* __restrict__ out)
{
  __shared__ __align__(16) char smem[63328];
  __hip_bfloat16* Ybuf = (__hip_bfloat16*)(smem);           // 118 x 136  32096
  __hip_bfloat16* sQP  = (__hip_bfloat16*)(smem + 32096);   // 128 x 40   10240
  __hip_bfloat16* sK   = (__hip_bfloat16*)(smem + 42336);   // 128 x 40   10240
  __hip_bfloat16* sVt  = (__hip_bfloat16*)(smem + 52576);   //  32 x 136   8704
  float*          sCb  = (float*)        (smem + 61280);    // 512 f32     2048

  const __hip_bfloat16* wq  = wbf;
  const __hip_bfloat16* wk  = wbf + 16384;
  const __hip_bfloat16* wvw = wbf + 32768;
  const __hip_bfloat16* w2  = wbf + 49152;

  const int b    = blockIdx.x;
  const int tid  = threadIdx.x;
  const int wv   = tid >> 6;        // wave 0..7 -> 16-row strip
  const int lane = tid & 63;
  const int c    = lane & 15;
  const int quad = lane >> 4;
  const int arow = wv*16 + c;       // this lane's M-row for A/ay fragments

  { // sCb: fc2_b(0..127) fc3_w(128..255) ln_g(256..383) ln_b(384..511)
    int i = tid;
    if (i < 512){
      float v;
      if      (i < 128) v = fc2_b[i];
      else if (i < 256) v = fc3_w[i-128];
      else if (i < 384) v = ln_g [i-256];
      else              v = ln_b [i-384];
      sCb[i] = v;
    }
  }
  __syncthreads();

  float o1[4];

  #pragma unroll 1
  for (int p = 0; p < 2; ++p){
    // ---- A fragments for this pass (registers only) ----
    short8 afr[4];
    if (p == 0){
      float xs = (arow < SEQ) ? x[b*SEQ + arow] : 0.f;
      #pragma unroll
      for (int k4 = 0; k4 < 4; k4++){
        int d0 = k4*32 + quad*8;
        short8 fr;
        #pragma unroll
        for (int i = 0; i < 8; i++){
          float z = xs * fc1_w[d0+i] + fc1_b[d0+i];
          float v = fsilu(z);
          if (arow >= SEQ) v = 0.f;             // pad rows exact zero
          fr[i] = (short)__builtin_bit_cast(unsigned short, __float2bfloat16(v));
        }
        afr[k4] = fr;
      }
    } else {
      #pragma unroll
      for (int k4 = 0; k4 < 4; k4++){
        short8 fr = *(const short8*)(Ybuf + arow*YS + k4*32 + quad*8);
        if (arow >= SEQ) fr = (short8){0,0,0,0,0,0,0,0};  // NaN guard for V path
        afr[k4] = fr;
      }
    }

    #pragma unroll 1
    for (int h = 0; h < 4; ++h){
      const float invf = exp2f((float)(4*c + h) * (-0.20762050593045f)); // 10000^(-d/64)

      { // ---- Q & K head GEMMs + RoPE -> sQP / sK (packed pair k-order) ----
        // Q written pre-scaled by KSC = 1/sqrt(32)/ln2: softmax is pure exp2.
        const __hip_bfloat16* wpq = wq + (h*32 + c)*128 + quad*8;
        const __hip_bfloat16* wpk = wk + (h*32 + c)*128 + quad*8;
        f32x4 q0={0,0,0,0}, q1={0,0,0,0}, k0={0,0,0,0}, k1={0,0,0,0};
        #pragma unroll
        for (int k4 = 0; k4 < 4; k4++){
          short8 bq0 = *(const short8*)(wpq + k4*32);
          short8 bq1 = *(const short8*)(wpq + 2048 + k4*32);
          short8 bk0 = *(const short8*)(wpk + k4*32);
          short8 bk1 = *(const short8*)(wpk + 2048 + k4*32);
          q0 = mfma16(afr[k4], bq0, q0);
          q1 = mfma16(afr[k4], bq1, q1);
          k0 = mfma16(afr[k4], bk0, k0);
          k1 = mfma16(afr[k4], bk1, k1);
        }
        const float KSC = 0.25500526963f;   // (1/sqrt(32)) * (1/ln2)
        float bQ0 = qkv_b[      4*c + h], bQ1 = qkv_b[ 64 + 4*c + h];
        float bK0 = qkv_b[128 + 4*c + h], bK1 = qkv_b[192 + 4*c + h];
        #pragma unroll
        for (int j = 0; j < 4; j++){
          int s = wv*16 + quad*4 + j;
          float ang = (float)s * invf;
          float cv = bfr(__cosf(ang)), sv = bfr(__sinf(ang));
          float cvq = cv*KSC, svq = sv*KSC;
          float xq1 = q0[j] + bQ0, xq2 = q1[j] + bQ1;
          float xk1 = k0[j] + bK0, xk2 = k1[j] + bK1;
          *(unsigned*)(sQP + s*SQS + 2*c) = pack_bf2( xq1*cvq + xq2*svq, -xq1*svq + xq2*cvq);
          *(unsigned*)(sK  + s*SQS + 2*c) = pack_bf2( xk1*cv  + xk2*sv , -xk1*sv  + xk2*cv );
        }
      }
      { // ---- V head GEMM -> transposed sVt[dh][s] ----
        const __hip_bfloat16* wpv = wvw + (h*32 + c)*128 + quad*8;
        f32x4 v0={0,0,0,0}, v1={0,0,0,0};
        #pragma unroll
        for (int k4 = 0; k4 < 4; k4++){
          short8 b0 = *(const short8*)(wpv + k4*32);
          short8 b1 = *(const short8*)(wpv + 2048 + k4*32);
          v0 = mfma16(afr[k4], b0, v0);
          v1 = mfma16(afr[k4], b1, v1);
        }
        float bV0 = qkv_b[256 + 4*c + h], bV1 = qkv_b[320 + 4*c + h];
        int s0 = wv*16 + quad*4;
        *(unsigned*)(sVt + (c   )*SVS + s0    ) = pack_bf2(v0[0]+bV0, v0[1]+bV0);
        *(unsigned*)(sVt + (c   )*SVS + s0 + 2) = pack_bf2(v0[2]+bV0, v0[3]+bV0);
        *(unsigned*)(sVt + (c+16)*SVS + s0    ) = pack_bf2(v1[0]+bV1, v1[1]+bV1);
        *(unsigned*)(sVt + (c+16)*SVS + s0 + 2) = pack_bf2(v1[2]+bV1, v1[3]+bV1);
      }
      __syncthreads();   // K/Vt visible to all waves

      // ---- QK^T (causal tile skip) + softmax (exp2 domain, Q pre-scaled) ----
      short8 aq = *(const short8*)(sQP + arow*SQS + quad*8);
      f32x4 sc[8];
      #pragma unroll
      for (int t = 0; t < 8; t++){
        sc[t] = (f32x4){0.f,0.f,0.f,0.f};
        if (t <= wv){
          short8 bk = *(const short8*)(sK + (t*16 + c)*SQS + quad*8);
          f32x4 z = {0,0,0,0};
          sc[t] = mfma16(aq, bk, z);
        }
      }
      float rnorm[4];
      #pragma unroll
      for (int j = 0; j < 4; j++){
        float mx = -3.0e38f;
        #pragma unroll
        for (int t = 0; t < 8; t++){
          if (t < wv){                            // sub-diagonal: always valid
            mx = fmaxf(mx, sc[t][j]);
          } else if (t == wv){                    // diagonal tile: in-tile mask
            float v = (c <= quad*4 + j) ? sc[t][j] : -1.0e9f;
            sc[t][j] = v;
            mx = fmaxf(mx, v);
          }
        }
        mx = rmax16(mx);
        float sum = 0.f;
        #pragma unroll
        for (int t = 0; t < 8; t++) if (t <= wv){
          float e = exp2f(sc[t][j] - mx); sc[t][j] = e; sum += e;
        }
        sum = rsum16(sum);
        rnorm[j] = rcpf(sum);                     // applied to y after PV
      }

      // ---- P@V in 32-k quarters through sQP (wave-private; Q is dead) ----
      f32x4 y0 = {0,0,0,0}, y1 = {0,0,0,0};
      auto pv_quarter = [&](int qt, f32x4 pa, f32x4 pb){
        int s0 = wv*16 + quad*4;
        #pragma unroll
        for (int j = 0; j < 4; j++){
          sQP[(s0+j)*SQS + c     ] = __float2bfloat16(pa[j]);
          sQP[(s0+j)*SQS + 16 + c] = __float2bfloat16(pb[j]);
        }
        short8 ap  = *(const short8*)(sQP + arow*SQS + quad*8);
        short8 bv0 = *(const short8*)(sVt + (c   )*SVS + qt*32 + quad*8);
        short8 bv1 = *(const short8*)(sVt + (c+16)*SVS + qt*32 + quad*8);
        y0 = mfma16(ap, bv0, y0);
        y1 = mfma16(ap, bv1, y1);
      };
      int qmax = wv >> 1;
      pv_quarter(0, sc[0], sc[1]);
      if (qmax >= 1) pv_quarter(1, sc[2], sc[3]);
      if (qmax >= 2) pv_quarter(2, sc[4], sc[5]);
      if (qmax >= 3) pv_quarter(3, sc[6], sc[7]);
      #pragma unroll
      for (int j = 0; j < 4; j++){ y0[j] *= rnorm[j]; y1[j] *= rnorm[j]; }

      { // ---- Y -> Ybuf at this head's k'-slice (guarded: 118 rows only) ----
        int s0 = wv*16 + quad*4;
        #pragma unroll
        for (int j = 0; j < 4; j++)
          if (s0 + j < SEQ)
            *(unsigned*)(Ybuf + (s0+j)*YS + h*32 + 2*c) = pack_bf2(y0[j], y1[j]);
      }
      __syncthreads();   // all reads of K/Vt done; also fences Ybuf for FC2
    }

    // ================= FC2 (once per pass) + silu + LN / readout ==========
    short8 ay[4];
    #pragma unroll
    for (int k4 = 0; k4 < 4; k4++)
      ay[k4] = *(const short8*)(Ybuf + arow*YS + k4*32 + quad*8);
    f32x4 xx[8];
    f32x4 S1 = {0,0,0,0}, S2 = {0,0,0,0}, S3 = {0,0,0,0};
    #pragma unroll 1
    for (int t = 0; t < 8; t++){
      f32x4 acc = {0,0,0,0};
      #pragma unroll
      for (int k4 = 0; k4 < 4; k4++){
        short8 bw = *(const short8*)(w2 + (t*16 + c)*128 + k4*32 + quad*8);
        acc = mfma16(ay[k4], bw, acc);
      }
      float bias = sCb[t*16 + c];
      float w3   = sCb[128 + t*16 + c];
      #pragma unroll
      for (int j = 0; j < 4; j++){
        float v = fsilu(acc[j] + bias);
        xx[t][j] = v;
        S1[j] += v; S2[j] += v*v; S3[j] += v*w3;
      }
    }
    #pragma unroll
    for (int j = 0; j < 4; j++){
      float s1 = rsum16(S1[j]), s2 = rsum16(S2[j]), s3 = rsum16(S3[j]);
      int s = wv*16 + quad*4 + j;
      if (p == 0){
        float mu  = s1 * (1.f/128.f);
        float var = fmaxf(s2 * (1.f/128.f) - mu*mu, 0.f);
        float rs  = rsqrtf(var + 1e-5f);
        if (s < SEQ){
          #pragma unroll
          for (int t = 0; t < 8; t++){
            int d = t*16 + c;
            Ybuf[s*YS + d] = __float2bfloat16((xx[t][j] - mu)*rs*sCb[256+d] + sCb[384+d]);
          }
        }
        o1[j] = s3;                        // x1 . fc3_w residual readout
      } else {
        if (c == 0 && s < SEQ) out[b*SEQ + s] = o1[j] + s3 + fc3_b[0];
      }
    }
    if (p == 0) __syncthreads();   // fence LN writes before pass-1 afr reads
  }
}

extern "C" void kernel_launch(void* const* d_in, const int* in_sizes, int n_in,
                              void* d_out, int out_size, void* d_ws, size_t ws_size,
                              hipStream_t stream){
  const float* x     = (const float*)d_in[0];
  const float* fc1_w = (const float*)d_in[1];
  const float* fc1_b = (const float*)d_in[2];
  const float* qkv_w = (const float*)d_in[3];
  const float* qkv_b = (const float*)d_in[4];
  const float* fc2_w = (const float*)d_in[5];
  const float* fc2_b = (const float*)d_in[6];
  const float* fc3_w = (const float*)d_in[7];
  const float* fc3_b = (const float*)d_in[8];
  const float* ln_g  = (const float*)d_in[9];
  const float* ln_b  = (const float*)d_in[10];

  __hip_bfloat16* wbf = (__hip_bfloat16*)d_ws;   // 65536 bf16 = 128 KB
  prep_kernel<<<256, 256, 0, stream>>>(qkv_w, fc2_w, wbf);

  const int B = in_sizes[0] / SEQ;               // 8192
  fused_kernel<<<B, 512, 0, stream>>>(x, fc1_w, fc1_b, qkv_b, fc2_b, fc3_w, fc3_b,
                                      ln_g, ln_b, wbf, (float*)d_out);
}